// Round 17
// baseline (606.830 us; speedup 1.0000x reference)
//
#include <hip/hip_runtime.h>

// LSTMPricePredictor: B=4096, T=512, IN=1, H=50, 2 layers + FC(50->1)
// R17: 2 blocks/CU + one-layer-per-lane EW.
//   R16 (414 us): VALU issue 905 cyc/SIMD/step (trans 416 irreducible per
//   wave), ~890 cyc/step stall at 13 waves/CU (Occ 37%). Doubling blocks
//   naively doubles trans (EW runs on all 16 cols; 8 wasted at NB=8).
//   Fix: lanes col<8 do the layer-0 cell (own acc0); lanes col>=8 do the
//   layer-1 cell of col-8, acc1 moved by DPP row_ror:8 (xor-8 in the
//   16-lane row, full-rate VALU). 8 trans/wave -> trans/CU unchanged,
//   waves/CU doubled. Edge steps (u=0 layer-1, u=TT layer-0) handled by
//   predicated c-commit + masked h-store; loop body is straight-line.
// Structure else = R16 (passed, absmax 4.9e-4): weights = A operand
//   (row = 4*cell + gate, log2e pre-folded, raw v_exp_f32 EW); h = B
//   operand; x through MFMA k=50 slot; h double-buffered LDS B-layout;
//   1 barrier/step. 512 blocks x 832 threads (13 waves), NB=8 rows/block.

typedef _Float16 half8 __attribute__((ext_vector_type(8)));
typedef float    f32x4 __attribute__((ext_vector_type(4)));

#define TT   512
#define HID  50
#define NB   8          // batch rows per block (MFMA cols 8..15 unused/zero)
#define LOG2E 1.44269504f

// Weight A-fragment: lane's 8 fp16 for K-chunk `chunk`, pre-scaled by the
// gate's exp2 factor. Row m -> gate = m&3, cell = 4*wv + (m>>2).
// W is (200 x 50): element [gate*50+cell][k]. Layer-0 folds W_ih0 at k==50.
__device__ __forceinline__ float4 make_wfrag(const float* W, const float* Wx,
                                             int gate, int cell, int chunk,
                                             int quad, bool foldx, float scale) {
    half8 hv = {};
    #pragma unroll
    for (int j = 0; j < 8; ++j) {
        const int k = 32 * chunk + 8 * quad + j;
        float v = 0.0f;
        if (cell < HID) {
            if (k < HID)                 v = W[(gate * HID + cell) * HID + k] * scale;
            else if (foldx && k == HID)  v = Wx[gate * HID + cell] * scale;
        }
        hv[j] = (_Float16)v;
    }
    return __builtin_bit_cast(float4, hv);
}

// xor-8 lane swap within each 16-lane row: DPP row_ror:8 (full-rate VALU).
__device__ __forceinline__ float xor8(float v) {
    int i = __builtin_bit_cast(int, v);
    i = __builtin_amdgcn_mov_dpp(i, 0x128, 0xF, 0xF, true);  // row_ror:8
    return __builtin_bit_cast(float, i);
}

#define PIN(f) asm volatile("" : "+v"(f.x), "+v"(f.y), "+v"(f.z), "+v"(f.w));
#define MFMA(af, b, c) __builtin_amdgcn_mfma_f32_16x16x32_f16(__builtin_bit_cast(half8, (af)), (b), (c), 0, 0, 0)

extern "C" __global__ __launch_bounds__(832, 6)
void lstm2_mfma_kernel(const float* __restrict__ x,
                       const float* __restrict__ W_ih0, const float* __restrict__ W_hh0,
                       const float* __restrict__ b_ih0, const float* __restrict__ b_hh0,
                       const float* __restrict__ W_ih1, const float* __restrict__ W_hh1,
                       const float* __restrict__ b_ih1, const float* __restrict__ b_hh1,
                       const float* __restrict__ fc_w, const float* __restrict__ fc_b,
                       float* __restrict__ out)
{
    // h-state in B-fragment layout: element (k, n) at (k>>5)*512 +
    // (((k&31)>>3)*16 + n)*8 + (k&7). k<50 = h, k==50 = x slot (H0 only).
    // Only cols n<8 are ever written; cols 8..15 stay zero.
    __shared__ _Float16 H0[2][1024];
    __shared__ _Float16 H1[2][1024];
    __shared__ float    hfin[HID * NB];   // fp32 h1^(TT) for the FC epilogue

    const int tid  = threadIdx.x;
    const int lane = tid & 63;
    const int wv   = tid >> 6;            // wave 0..12 = gate-row tile
    const int b0   = blockIdx.x * NB;

    for (int i = tid; i < 1024; i += 832) {
        H0[0][i] = (_Float16)0.f; H0[1][i] = (_Float16)0.f;
        H1[0][i] = (_Float16)0.f; H1[1][i] = (_Float16)0.f;
    }

    const int quad = lane >> 4;
    const int col  = lane & 15;           // MFMA column; batch col = col&7
    const int col8 = col & 7;
    const bool isL0 = (col < 8);          // this lane's EW layer

    // ---- A-fragments (weights, exp2-prescaled), loaded once, pinned ----
    const int mrow  = lane & 15;          // A-row within tile
    const int gateA = mrow & 3;
    const int cellA = 4 * wv + (mrow >> 2);
    const float scA = (gateA == 2) ? 2.0f * LOG2E : -LOG2E;
    float4 A0c0 = make_wfrag(W_hh0, W_ih0, gateA, cellA, 0, quad, true,  scA);
    float4 A0c1 = make_wfrag(W_hh0, W_ih0, gateA, cellA, 1, quad, true,  scA);
    float4 Aic0 = make_wfrag(W_ih1, W_ih1, gateA, cellA, 0, quad, false, scA);
    float4 Aic1 = make_wfrag(W_ih1, W_ih1, gateA, cellA, 1, quad, false, scA);
    float4 Ahc0 = make_wfrag(W_hh1, W_hh1, gateA, cellA, 0, quad, false, scA);
    float4 Ahc1 = make_wfrag(W_hh1, W_hh1, gateA, cellA, 1, quad, false, scA);
    PIN(A0c0) PIN(A0c1) PIN(Aic0) PIN(Aic1) PIN(Ahc0) PIN(Ahc1)

    // ---- D-cell ownership: reg = gate, cell = 4*wv + quad ----
    const int  cellD = 4 * wv + quad;
    const bool ewok  = (cellD < HID);
    f32x4 bias0, bias1;
    #pragma unroll
    for (int g = 0; g < 4; ++g) {
        const float s = (g == 2) ? 2.0f * LOG2E : -LOG2E;
        bias0[g] = ewok ? (b_ih0[g * HID + cellD] + b_hh0[g * HID + cellD]) * s : 0.f;
        bias1[g] = ewok ? (b_ih1[g * HID + cellD] + b_hh1[g * HID + cellD]) * s : 0.f;
    }
    // h write-back index in B-layout for (cellD, col8)
    const int wi = (cellD >> 5) * 512 + (((cellD & 31) >> 3) * 16 + col8) * 8 + (cellD & 7);

    // x_0 into H0[0]'s x slot: k=50 -> chunk1, quad'=2, j=2 (cols 0..7)
    if (tid < NB) H0[0][512 + (32 + tid) * 8 + 2] = (_Float16)x[(size_t)(b0 + tid) * TT];

    float cst = 0.f;   // this lane's cell state (layer-0 if isL0, else layer-1)
    __syncthreads();

    #pragma unroll 2
    for (int u = 0; u <= TT; ++u) {
        const int pu = u & 1, pn = pu ^ 1;

        half8 b0c0 = *(half8*)(&H0[pu][lane * 8]);
        half8 b0c1 = *(half8*)(&H0[pu][512 + lane * 8]);
        half8 b1c0 = *(half8*)(&H1[pn][lane * 8]);
        half8 b1c1 = *(half8*)(&H1[pn][512 + lane * 8]);

        float xr = 0.f;
        if (tid < NB && (u + 1) < TT)
            xr = x[(size_t)(b0 + tid) * TT + u + 1];   // issue early (L1-resident)

        // ---- GEMMs (straight-line; edge junk killed by predicated commit) ----
        f32x4 acc0 = bias0;
        acc0 = MFMA(A0c0, b0c0, acc0);
        acc0 = MFMA(A0c1, b0c1, acc0);                 // x slot k=50 included
        f32x4 acc1 = bias1;
        acc1 = MFMA(Aic0, b0c0, acc1);                 // Wi1 . h0^u
        acc1 = MFMA(Aic1, b0c1, acc1);                 // (x slot hits zero rows)
        acc1 = MFMA(Ahc0, b1c0, acc1);                 // Wh1 . h1^{u-1}
        acc1 = MFMA(Ahc1, b1c1, acc1);

        // ---- one-layer-per-lane EW ----
        f32x4 am;
        #pragma unroll
        for (int r = 0; r < 4; ++r) {
            const float sw = xor8(acc1[r]);            // acc1 of partner col
            am[r] = isL0 ? acc0[r] : sw;
        }
        const bool valid = isL0 ? (u != TT) : (u != 0);

        const float ei = __builtin_amdgcn_exp2f(am[0]);   // e^{-i}
        const float ef = __builtin_amdgcn_exp2f(am[1]);   // e^{-f}
        const float eg = __builtin_amdgcn_exp2f(am[2]);   // e^{2g}
        const float eo = __builtin_amdgcn_exp2f(am[3]);   // e^{-o}
        const float itg = (eg - 1.0f) *
            __builtin_amdgcn_rcpf((1.0f + ei) * (eg + 1.0f));   // sig(i)*tanh(g)
        const float sf = __builtin_amdgcn_rcpf(1.0f + ef);      // sig(f)
        const float cn = sf * cst + itg;
        const float ec = __builtin_amdgcn_exp2f(cn * (2.0f * LOG2E));  // e^{2c}
        const float h  = (ec - 1.0f) *
            __builtin_amdgcn_rcpf((1.0f + eo) * (ec + 1.0f));   // sig(o)*tanh(c)

        if (valid) cst = cn;                            // predicated commit
        _Float16* dst = isL0 ? &H0[pn][wi] : &H1[pu][wi];
        if (valid && ewok) *dst = (_Float16)h;
        if (u == TT && !isL0 && ewok) hfin[cellD * NB + col8] = h;

        if (tid < NB && (u + 1) < TT)
            H0[pn][512 + (32 + tid) * 8 + 2] = (_Float16)xr;   // x_{u+1} slot
        __syncthreads();
    }

    // ---------- FC epilogue: out[b] = fc_b + fc_w . h1^(TT)[b,:] ----------
    if (tid < NB) {
        float s = fc_b[0];
        for (int k = 0; k < HID; ++k)
            s += fc_w[k] * hfin[k * NB + tid];
        out[b0 + tid] = s;
    }
}

extern "C" void kernel_launch(void* const* d_in, const int* in_sizes, int n_in,
                              void* d_out, int out_size, void* d_ws, size_t ws_size,
                              hipStream_t stream) {
    (void)in_sizes; (void)n_in; (void)d_ws; (void)ws_size; (void)out_size;
    const float* x     = (const float*)d_in[0];
    const float* W_ih0 = (const float*)d_in[1];
    const float* W_hh0 = (const float*)d_in[2];
    const float* b_ih0 = (const float*)d_in[3];
    const float* b_hh0 = (const float*)d_in[4];
    const float* W_ih1 = (const float*)d_in[5];
    const float* W_hh1 = (const float*)d_in[6];
    const float* b_ih1 = (const float*)d_in[7];
    const float* b_hh1 = (const float*)d_in[8];
    const float* fc_w  = (const float*)d_in[9];
    const float* fc_b  = (const float*)d_in[10];

    dim3 grid(4096 / NB);   // 512 blocks -> 2 per CU (26 waves/CU)
    dim3 block(832);        // 13 waves
    lstm2_mfma_kernel<<<grid, block, 0, stream>>>(
        x, W_ih0, W_hh0, b_ih0, b_hh0,
        W_ih1, W_hh1, b_ih1, b_hh1,
        fc_w, fc_b, (float*)d_out);
}

// Round 18
// 485.825 us; speedup vs baseline: 1.2491x; 1.2491x over previous
//
#include <hip/hip_runtime.h>

// LSTMPricePredictor: B=4096, T=512, IN=1, H=50, 2 layers + FC(50->1)
// R18: co-residency-safe 2 blocks/CU + fused single-buffer B operand.
//   R17 post-mortem: 832-thread (13-wave) blocks DON'T pack 2/CU (Occ stuck
//   38.6% -> serialized, 607 us); R10 showed 1024-thread blocks DO (74%).
//   So: 1024 threads (16 waves; waves 13..15 just barrier), grid 512, NB=8.
//   NB=8 lets h0 (cols 0..7) and h1 (cols 8..15) share ONE B buffer:
//     gates0 = bias0 + A_hh0.B           (D cols 0..7 valid)
//     gates1 = bias1 + Wi1.h0 + Wh1.h1 = acc_i[col-8 via DPP] + acc_h[col]
//   -> 2 ds_read_b128/lane-step (was 4): DS pipe/CU same as R16 at 2x waves.
//   One-layer-per-lane EW (8 trans/lane): col<8 -> layer-0 cell, col>=8 ->
//   layer-1 cell of col-8. Both layers write the SAME next buffer H[pn]
//   with one index formula. Edge steps via predicated commit/store.
// Carried from R16 (passed, absmax 4.9e-4): weights = A operand
//   (row = 4*cell + gate, log2e pre-folded), raw v_exp_f32 + rcp EW,
//   x through MFMA k=50 slot (cols 0..7), 1 barrier/step.

typedef _Float16 half8 __attribute__((ext_vector_type(8)));
typedef float    f32x4 __attribute__((ext_vector_type(4)));

#define TT   512
#define HID  50
#define NB   8          // batch rows per block
#define LOG2E 1.44269504f

// Weight A-fragment: lane's 8 fp16 for K-chunk `chunk`, pre-scaled by the
// gate's exp2 factor. Row m -> gate = m&3, cell = 4*wv + (m>>2).
// W is (200 x 50): element [gate*50+cell][k]. Layer-0 folds W_ih0 at k==50.
__device__ __forceinline__ float4 make_wfrag(const float* W, const float* Wx,
                                             int gate, int cell, int chunk,
                                             int quad, bool foldx, float scale) {
    half8 hv = {};
    #pragma unroll
    for (int j = 0; j < 8; ++j) {
        const int k = 32 * chunk + 8 * quad + j;
        float v = 0.0f;
        if (cell < HID) {
            if (k < HID)                 v = W[(gate * HID + cell) * HID + k] * scale;
            else if (foldx && k == HID)  v = Wx[gate * HID + cell] * scale;
        }
        hv[j] = (_Float16)v;
    }
    return __builtin_bit_cast(float4, hv);
}

// xor-8 lane swap within each 16-lane row: DPP row_ror:8 (full-rate VALU).
__device__ __forceinline__ float xor8(float v) {
    int i = __builtin_bit_cast(int, v);
    i = __builtin_amdgcn_mov_dpp(i, 0x128, 0xF, 0xF, true);  // row_ror:8
    return __builtin_bit_cast(float, i);
}

#define PIN(f) asm volatile("" : "+v"(f.x), "+v"(f.y), "+v"(f.z), "+v"(f.w));
#define MFMA(af, b, c) __builtin_amdgcn_mfma_f32_16x16x32_f16(__builtin_bit_cast(half8, (af)), (b), (c), 0, 0, 0)

extern "C" __global__ __launch_bounds__(1024, 8)
void lstm2_mfma_kernel(const float* __restrict__ x,
                       const float* __restrict__ W_ih0, const float* __restrict__ W_hh0,
                       const float* __restrict__ b_ih0, const float* __restrict__ b_hh0,
                       const float* __restrict__ W_ih1, const float* __restrict__ W_hh1,
                       const float* __restrict__ b_ih1, const float* __restrict__ b_hh1,
                       const float* __restrict__ fc_w, const float* __restrict__ fc_b,
                       float* __restrict__ out)
{
    // Fused h-state in B-fragment layout: element (k, n) at (k>>5)*512 +
    // (((k&31)>>3)*16 + n)*8 + (k&7). n<8: h0 (k<50; k==50 = x slot);
    // n>=8: h1 of batch n-8 (k<50). Buffer pu holds [h0^u | h1^{u-1}].
    __shared__ _Float16 H[2][1024];
    __shared__ float    hfin[HID * NB];   // fp32 h1^(TT) for the FC epilogue

    const int tid  = threadIdx.x;
    const int lane = tid & 63;
    const int wv   = tid >> 6;            // wave 0..15; 0..12 = gate-row tile
    const int b0   = blockIdx.x * NB;
    const bool active = (wv < 13);

    H[0][tid] = (_Float16)0.f;
    H[1][tid] = (_Float16)0.f;

    const int quad = lane >> 4;
    const int col  = lane & 15;           // MFMA column
    const bool isL0 = (col < 8);          // lane's EW layer; batch = col or col-8

    // ---- A-fragments (weights, exp2-prescaled), loaded once, pinned ----
    const int mrow  = lane & 15;          // A-row within tile
    const int gateA = mrow & 3;
    const int cellA = 4 * wv + (mrow >> 2);       // >= HID for wv >= 13 -> zeros
    const float scA = (gateA == 2) ? 2.0f * LOG2E : -LOG2E;
    float4 A0c0 = make_wfrag(W_hh0, W_ih0, gateA, cellA, 0, quad, true,  scA);
    float4 A0c1 = make_wfrag(W_hh0, W_ih0, gateA, cellA, 1, quad, true,  scA);
    float4 Aic0 = make_wfrag(W_ih1, W_ih1, gateA, cellA, 0, quad, false, scA);
    float4 Aic1 = make_wfrag(W_ih1, W_ih1, gateA, cellA, 1, quad, false, scA);
    float4 Ahc0 = make_wfrag(W_hh1, W_hh1, gateA, cellA, 0, quad, false, scA);
    float4 Ahc1 = make_wfrag(W_hh1, W_hh1, gateA, cellA, 1, quad, false, scA);
    PIN(A0c0) PIN(A0c1) PIN(Aic0) PIN(Aic1) PIN(Ahc0) PIN(Ahc1)

    // ---- D-cell ownership: reg = gate, cell = 4*wv + quad ----
    const int  cellD = 4 * wv + quad;
    const bool ewok  = (cellD < HID);
    f32x4 bias0, bias1;
    #pragma unroll
    for (int g = 0; g < 4; ++g) {
        const float s = (g == 2) ? 2.0f * LOG2E : -LOG2E;
        bias0[g] = ewok ? (b_ih0[g * HID + cellD] + b_hh0[g * HID + cellD]) * s : 0.f;
        bias1[g] = ewok ? (b_ih1[g * HID + cellD] + b_hh1[g * HID + cellD]) * s : 0.f;
    }
    // h write-back index: (k=cellD, n=col) -- same formula for both layers
    const int wi = (cellD >> 5) * 512 + (((cellD & 31) >> 3) * 16 + col) * 8 + (cellD & 7);

    // x_0 into H[0]'s x slot: k=50 -> chunk1, lane'=32+b, j=2 (cols 0..7)
    if (tid < NB) H[0][512 + (32 + tid) * 8 + 2] = (_Float16)x[(size_t)(b0 + tid) * TT];

    float cst = 0.f;   // cell state: layer-0 (isL0) or layer-1 (else)
    __syncthreads();

    #pragma unroll 2
    for (int u = 0; u <= TT; ++u) {
        const int pu = u & 1, pn = pu ^ 1;

        float xr = 0.f;
        if (tid < NB && (u + 1) < TT)
            xr = x[(size_t)(b0 + tid) * TT + u + 1];   // issue early (L1-resident)

        if (active) {
            half8 bc0 = *(half8*)(&H[pu][lane * 8]);
            half8 bc1 = *(half8*)(&H[pu][512 + lane * 8]);

            f32x4 acc0 = bias0;                        // layer-0 gates (cols 0..7)
            acc0 = MFMA(A0c0, bc0, acc0);
            acc0 = MFMA(A0c1, bc1, acc0);              // x slot k=50 included
            f32x4 acci = bias1;                        // Wi1 . h0 (cols 0..7)
            acci = MFMA(Aic0, bc0, acci);
            acci = MFMA(Aic1, bc1, acci);
            f32x4 acch = {0.f, 0.f, 0.f, 0.f};         // Wh1 . h1 (cols 8..15)
            acch = MFMA(Ahc0, bc0, acch);
            acch = MFMA(Ahc1, bc1, acch);

            // one-layer-per-lane gate select
            f32x4 am;
            #pragma unroll
            for (int r = 0; r < 4; ++r) {
                const float g1 = xor8(acci[r]) + acch[r];   // gates1 (cols 8..15)
                am[r] = isL0 ? acc0[r] : g1;
            }
            const bool valid = isL0 ? (u != TT) : (u != 0);

            const float ei = __builtin_amdgcn_exp2f(am[0]);   // e^{-i}
            const float ef = __builtin_amdgcn_exp2f(am[1]);   // e^{-f}
            const float eg = __builtin_amdgcn_exp2f(am[2]);   // e^{2g}
            const float eo = __builtin_amdgcn_exp2f(am[3]);   // e^{-o}
            const float itg = (eg - 1.0f) *
                __builtin_amdgcn_rcpf((1.0f + ei) * (eg + 1.0f));   // sig(i)*tanh(g)
            const float sf = __builtin_amdgcn_rcpf(1.0f + ef);      // sig(f)
            const float cn = sf * cst + itg;
            const float ec = __builtin_amdgcn_exp2f(cn * (2.0f * LOG2E));  // e^{2c}
            const float h  = (ec - 1.0f) *
                __builtin_amdgcn_rcpf((1.0f + eo) * (ec + 1.0f));   // sig(o)*tanh(c)

            if (valid) cst = cn;                       // predicated commit
            if (valid && ewok) H[pn][wi] = (_Float16)h; // h0^{u+1} / h1^u
            if (u == TT && !isL0 && ewok) hfin[cellD * NB + (col - 8)] = h;
        }
        if (tid < NB && (u + 1) < TT)
            H[pn][512 + (32 + tid) * 8 + 2] = (_Float16)xr;   // x_{u+1} slot
        __syncthreads();
    }

    // ---------- FC epilogue: out[b] = fc_b + fc_w . h1^(TT)[b,:] ----------
    if (tid < NB) {
        float s = fc_b[0];
        for (int k = 0; k < HID; ++k)
            s += fc_w[k] * hfin[k * NB + tid];
        out[b0 + tid] = s;
    }
}

extern "C" void kernel_launch(void* const* d_in, const int* in_sizes, int n_in,
                              void* d_out, int out_size, void* d_ws, size_t ws_size,
                              hipStream_t stream) {
    (void)in_sizes; (void)n_in; (void)d_ws; (void)ws_size; (void)out_size;
    const float* x     = (const float*)d_in[0];
    const float* W_ih0 = (const float*)d_in[1];
    const float* W_hh0 = (const float*)d_in[2];
    const float* b_ih0 = (const float*)d_in[3];
    const float* b_hh0 = (const float*)d_in[4];
    const float* W_ih1 = (const float*)d_in[5];
    const float* W_hh1 = (const float*)d_in[6];
    const float* b_ih1 = (const float*)d_in[7];
    const float* b_hh1 = (const float*)d_in[8];
    const float* fc_w  = (const float*)d_in[9];
    const float* fc_b  = (const float*)d_in[10];

    dim3 grid(4096 / NB);   // 512 blocks -> 2 per CU (proven to pack at 1024 thr)
    dim3 block(1024);       // 16 waves; waves 13..15 barrier-only
    lstm2_mfma_kernel<<<grid, block, 0, stream>>>(
        x, W_ih0, W_hh0, b_ih0, b_hh0,
        W_ih1, W_hh1, b_ih1, b_hh1,
        fc_w, fc_b, (float*)d_out);
}

// Round 19
// 432.409 us; speedup vs baseline: 1.4034x; 1.1235x over previous
//
#include <hip/hip_runtime.h>

// LSTMPricePredictor: B=4096, T=512, IN=1, H=50, 2 layers + FC(50->1)
// R19 = R16 (best: 414 us) + two surgical cuts. R17/R18 falsified the
//   occupancy path (832-thr blocks don't pack; 1024-thr packing doubles
//   per-wave overhead for zero stall reduction). R16's 13-wave NB=16 shape
//   is the efficiency optimum; attack its critical path instead:
//   (a) acc1 split acci+acch: 4 serial accumulating MFMAs -> two
//       independent 2-chains + 1 add (~-40 cyc chain/step);
//   (b) fused sf/itg reciprocal: R = rcp((1+ef)(1+ei)(eg+1)) yields both
//       sig(f) and sig(i)*tanh(g) -> 7 trans/cell (was 8), 14/lane-step.
// Carried from R16 (passed, absmax 4.9e-4): 256 blocks (1/CU) x 832
//   threads (13 waves); weights = A operand (row = 4*cell + gate, log2e
//   pre-folded); h = B operand (N = batch = 16); x through MFMA k=50 slot;
//   D[row=4*quad+reg][col] => lane's 4 acc regs = i,f,g,o of its cell/col;
//   raw v_exp_f32 + v_rcp_f32 EW in-register; h double-buffered LDS
//   B-layout; 1 barrier/step.

typedef _Float16 half8 __attribute__((ext_vector_type(8)));
typedef float    f32x4 __attribute__((ext_vector_type(4)));

#define TT   512
#define HID  50
#define NB   16         // batch rows per block
#define LOG2E 1.44269504f

// Weight A-fragment: lane's 8 fp16 for K-chunk `chunk`, pre-scaled by the
// gate's exp2 factor. Row m -> gate = m&3, cell = 4*wv + (m>>2).
// W is (200 x 50): element [gate*50+cell][k]. Layer-0 folds W_ih0 at k==50
// (the x slot), same scale.
__device__ __forceinline__ float4 make_wfrag(const float* W, const float* Wx,
                                             int gate, int cell, int chunk,
                                             int quad, bool foldx, float scale) {
    half8 hv = {};
    #pragma unroll
    for (int j = 0; j < 8; ++j) {
        const int k = 32 * chunk + 8 * quad + j;
        float v = 0.0f;
        if (cell < HID) {
            if (k < HID)                 v = W[(gate * HID + cell) * HID + k] * scale;
            else if (foldx && k == HID)  v = Wx[gate * HID + cell] * scale;
        }
        hv[j] = (_Float16)v;
    }
    return __builtin_bit_cast(float4, hv);
}

// Shared-rcp LSTM cell update on pre-scaled gates, RAW hardware exp2:
//   a0 = -i*log2e, a1 = -f*log2e, a2 = 2g*log2e, a3 = -o*log2e.
// One rcp serves both sig(f) and sig(i)*tanh(g):
//   P = (1+ei)(eg+1); R = rcp((1+ef)*P); sf = P*R; itg = (eg-1)(1+ef)*R.
__device__ __forceinline__ float cell_update(const f32x4 a, float& c) {
    const float ei = __builtin_amdgcn_exp2f(a[0]);   // e^{-i}
    const float ef = __builtin_amdgcn_exp2f(a[1]);   // e^{-f}
    const float eg = __builtin_amdgcn_exp2f(a[2]);   // e^{2g}
    const float eo = __builtin_amdgcn_exp2f(a[3]);   // e^{-o}
    const float fp = 1.0f + ef;
    const float P  = (1.0f + ei) * (eg + 1.0f);
    const float R  = __builtin_amdgcn_rcpf(fp * P);
    const float sf  = P * R;                         // sig(f)
    const float itg = (eg - 1.0f) * fp * R;          // sig(i)*tanh(g)
    c = sf * c + itg;
    const float ec = __builtin_amdgcn_exp2f(c * (2.0f * LOG2E));  // e^{2c}
    return (ec - 1.0f) *
        __builtin_amdgcn_rcpf((1.0f + eo) * (ec + 1.0f));   // sig(o)*tanh(c)
}

#define PIN(f) asm volatile("" : "+v"(f.x), "+v"(f.y), "+v"(f.z), "+v"(f.w));
#define MFMA(af, b, c) __builtin_amdgcn_mfma_f32_16x16x32_f16(__builtin_bit_cast(half8, (af)), (b), (c), 0, 0, 0)

extern "C" __global__ __launch_bounds__(832, 4)
void lstm2_mfma_kernel(const float* __restrict__ x,
                       const float* __restrict__ W_ih0, const float* __restrict__ W_hh0,
                       const float* __restrict__ b_ih0, const float* __restrict__ b_hh0,
                       const float* __restrict__ W_ih1, const float* __restrict__ W_hh1,
                       const float* __restrict__ b_ih1, const float* __restrict__ b_hh1,
                       const float* __restrict__ fc_w, const float* __restrict__ fc_b,
                       float* __restrict__ out)
{
    // h-state in B-fragment layout: element (k, n) at (k>>5)*512 +
    // (((k&31)>>3)*16 + n)*8 + (k&7). k<50 = h, k==50 = x slot (H0 only).
    __shared__ _Float16 H0[2][1024];
    __shared__ _Float16 H1[2][1024];
    __shared__ float    hfin[HID * NB];   // fp32 h1^(TT) for the FC epilogue

    const int tid  = threadIdx.x;
    const int lane = tid & 63;
    const int wv   = tid >> 6;            // wave 0..12 = gate-row tile
    const int b0   = blockIdx.x * NB;

    for (int i = tid; i < 1024; i += 832) {
        H0[0][i] = (_Float16)0.f; H0[1][i] = (_Float16)0.f;
        H1[0][i] = (_Float16)0.f; H1[1][i] = (_Float16)0.f;
    }

    const int quad = lane >> 4;
    const int col  = lane & 15;           // batch column

    // ---- A-fragments (weights, exp2-prescaled), loaded once, pinned ----
    const int mrow  = lane & 15;          // A-row within tile
    const int gateA = mrow & 3;
    const int cellA = 4 * wv + (mrow >> 2);
    const float scA = (gateA == 2) ? 2.0f * LOG2E : -LOG2E;
    float4 A0c0 = make_wfrag(W_hh0, W_ih0, gateA, cellA, 0, quad, true,  scA);
    float4 A0c1 = make_wfrag(W_hh0, W_ih0, gateA, cellA, 1, quad, true,  scA);
    float4 Aic0 = make_wfrag(W_ih1, W_ih1, gateA, cellA, 0, quad, false, scA);
    float4 Aic1 = make_wfrag(W_ih1, W_ih1, gateA, cellA, 1, quad, false, scA);
    float4 Ahc0 = make_wfrag(W_hh1, W_hh1, gateA, cellA, 0, quad, false, scA);
    float4 Ahc1 = make_wfrag(W_hh1, W_hh1, gateA, cellA, 1, quad, false, scA);
    PIN(A0c0) PIN(A0c1) PIN(Aic0) PIN(Aic1) PIN(Ahc0) PIN(Ahc1)

    // ---- D-cell ownership: reg = gate, cell = 4*wv + quad, batch = col ----
    const int  cellD = 4 * wv + quad;
    const bool ewok  = (cellD < HID);
    f32x4 bias0, bias1;
    #pragma unroll
    for (int g = 0; g < 4; ++g) {
        const float s = (g == 2) ? 2.0f * LOG2E : -LOG2E;
        bias0[g] = ewok ? (b_ih0[g * HID + cellD] + b_hh0[g * HID + cellD]) * s : 0.f;
        bias1[g] = ewok ? (b_ih1[g * HID + cellD] + b_hh1[g * HID + cellD]) * s : 0.f;
    }
    // h write-back index in B-layout for (cellD, col)
    const int wi = (cellD >> 5) * 512 + (((cellD & 31) >> 3) * 16 + col) * 8 + (cellD & 7);

    // x_0 into H0[0]'s x slot: k=50 -> chunk1, lane'=32+m, j=2
    if (tid < NB) H0[0][512 + (32 + tid) * 8 + 2] = (_Float16)x[(size_t)(b0 + tid) * TT];

    float c0 = 0.f, c1 = 0.f;
    __syncthreads();

    #pragma unroll 2
    for (int u = 0; u <= TT; ++u) {
        const int pu = u & 1, pn = pu ^ 1;

        half8 b0c0 = *(half8*)(&H0[pu][lane * 8]);
        half8 b0c1 = *(half8*)(&H0[pu][512 + lane * 8]);

        float xr = 0.f;
        if (tid < NB && (u + 1) < TT)
            xr = x[(size_t)(b0 + tid) * TT + u + 1];   // issue early (L1-resident)

        if (u != TT) {   // ---- layer-0: gates0^u + in-register EW ----
            f32x4 acc = bias0;
            acc = MFMA(A0c0, b0c0, acc);
            acc = MFMA(A0c1, b0c1, acc);               // x slot k=50 included
            const float h = cell_update(acc, c0);
            if (ewok) H0[pn][wi] = (_Float16)h;        // h0^{u+1}
        }
        if (u != 0) {    // ---- layer-1: gates1^{u-1} + in-register EW ----
            half8 b1c0 = *(half8*)(&H1[pn][lane * 8]);
            half8 b1c1 = *(half8*)(&H1[pn][512 + lane * 8]);
            // split accumulators: two independent 2-chains (shorter MFMA
            // serial latency than one 4-chain), summed in VALU.
            f32x4 acci = bias1;
            acci = MFMA(Aic0, b0c0, acci);             // Wi1 . h0^u
            acci = MFMA(Aic1, b0c1, acci);             // (x slot hits zero rows)
            f32x4 acch = {0.f, 0.f, 0.f, 0.f};
            acch = MFMA(Ahc0, b1c0, acch);             // Wh1 . h1^{u-1}
            acch = MFMA(Ahc1, b1c1, acch);
            f32x4 am;
            #pragma unroll
            for (int r = 0; r < 4; ++r) am[r] = acci[r] + acch[r];
            const float h = cell_update(am, c1);
            if (ewok) {
                H1[pu][wi] = (_Float16)h;              // h1^u
                if (u == TT) hfin[cellD * NB + col] = h;
            }
        }
        if (tid < NB && (u + 1) < TT)
            H0[pn][512 + (32 + tid) * 8 + 2] = (_Float16)xr;   // x_{u+1} slot
        __syncthreads();
    }

    // ---------- FC epilogue: out[b] = fc_b + fc_w . h1^(TT)[b,:] ----------
    if (tid < NB) {
        float s = fc_b[0];
        for (int k = 0; k < HID; ++k)
            s += fc_w[k] * hfin[k * NB + tid];
        out[b0 + tid] = s;
    }
}

extern "C" void kernel_launch(void* const* d_in, const int* in_sizes, int n_in,
                              void* d_out, int out_size, void* d_ws, size_t ws_size,
                              hipStream_t stream) {
    (void)in_sizes; (void)n_in; (void)d_ws; (void)ws_size; (void)out_size;
    const float* x     = (const float*)d_in[0];
    const float* W_ih0 = (const float*)d_in[1];
    const float* W_hh0 = (const float*)d_in[2];
    const float* b_ih0 = (const float*)d_in[3];
    const float* b_hh0 = (const float*)d_in[4];
    const float* W_ih1 = (const float*)d_in[5];
    const float* W_hh1 = (const float*)d_in[6];
    const float* b_ih1 = (const float*)d_in[7];
    const float* b_hh1 = (const float*)d_in[8];
    const float* fc_w  = (const float*)d_in[9];
    const float* fc_b  = (const float*)d_in[10];

    dim3 grid(4096 / NB);   // 256 blocks, 1 per CU
    dim3 block(832);        // 13 waves
    lstm2_mfma_kernel<<<grid, block, 0, stream>>>(
        x, W_ih0, W_hh0, b_ih0, b_hh0,
        W_ih1, W_hh1, b_ih1, b_hh1,
        fc_w, fc_b, (float*)d_out);
}

// Round 20
// 423.903 us; speedup vs baseline: 1.4315x; 1.0201x over previous
//
#include <hip/hip_runtime.h>

// LSTMPricePredictor: B=4096, T=512, IN=1, H=50, 2 layers + FC(50->1)
// R20 = R16 re-land (session best: 414 us, steady 383) + one free trim
//   (hoisted x row pointer). R19's two "cuts" both regressed (acc-split
//   added VALU for nothing -- MFMA chain latency wasn't critical; fused
//   rcp put muls on the serial c-chain -- trans pipe wasn't binding).
// Session map (all measured): R17 13-wave 2-blocks/CU -> blocks don't
//   pack (607); R18 16-wave packing -> per-wave overhead doubles, stall
//   unchanged (486); R19 chain/trans cuts -> regress (432). R16's shape
//   is the verified optimum: ~1795 cyc/step = ~905 VALU issue + ~650 DS
//   + latency residue at 3.25 waves/SIMD. fp8/MX K=128 (the remaining 2x
//   lever on DS+MFMA) is barred by precision: e4m3 ~1e-2 >> 1.63e-3
//   threshold; fp16's 2^-11 = the observed 4.9e-4.
// Structure: 256 blocks (1/CU) x 832 threads (13 waves); weights = A
//   operand (row = 4*cell + gate, log2e pre-folded into fp16 frags);
//   h = B operand (N = batch = 16); x via MFMA k=50 slot;
//   D[row=4*quad+reg][col] => lane's 4 acc regs = i,f,g,o of its cell/col;
//   raw v_exp_f32 + v_rcp_f32 shared-rcp EW in-register; h double-buffered
//   LDS B-layout; 1 barrier/step.

typedef _Float16 half8 __attribute__((ext_vector_type(8)));
typedef float    f32x4 __attribute__((ext_vector_type(4)));

#define TT   512
#define HID  50
#define NB   16         // batch rows per block
#define LOG2E 1.44269504f

// Weight A-fragment: lane's 8 fp16 for K-chunk `chunk`, pre-scaled by the
// gate's exp2 factor. Row m -> gate = m&3, cell = 4*wv + (m>>2).
// W is (200 x 50): element [gate*50+cell][k]. Layer-0 folds W_ih0 at k==50
// (the x slot), same scale.
__device__ __forceinline__ float4 make_wfrag(const float* W, const float* Wx,
                                             int gate, int cell, int chunk,
                                             int quad, bool foldx, float scale) {
    half8 hv = {};
    #pragma unroll
    for (int j = 0; j < 8; ++j) {
        const int k = 32 * chunk + 8 * quad + j;
        float v = 0.0f;
        if (cell < HID) {
            if (k < HID)                 v = W[(gate * HID + cell) * HID + k] * scale;
            else if (foldx && k == HID)  v = Wx[gate * HID + cell] * scale;
        }
        hv[j] = (_Float16)v;
    }
    return __builtin_bit_cast(float4, hv);
}

// Shared-rcp LSTM cell update on pre-scaled gates, RAW hardware exp2:
//   a0 = -i*log2e, a1 = -f*log2e, a2 = 2g*log2e, a3 = -o*log2e.
// All exp2 args are |a| <= ~45 -- no denormal guards needed (R15->R16: the
// strict llvm.exp2 lowering's guard sequence cost ~150 us).
__device__ __forceinline__ float cell_update(const f32x4 a, float& c) {
    const float ei = __builtin_amdgcn_exp2f(a[0]);   // e^{-i}
    const float ef = __builtin_amdgcn_exp2f(a[1]);   // e^{-f}
    const float eg = __builtin_amdgcn_exp2f(a[2]);   // e^{2g}
    const float eo = __builtin_amdgcn_exp2f(a[3]);   // e^{-o}
    const float itg = (eg - 1.0f) *
        __builtin_amdgcn_rcpf((1.0f + ei) * (eg + 1.0f));   // sig(i)*tanh(g)
    const float sf = __builtin_amdgcn_rcpf(1.0f + ef);      // sig(f)
    c = sf * c + itg;
    const float ec = __builtin_amdgcn_exp2f(c * (2.0f * LOG2E));  // e^{2c}
    return (ec - 1.0f) *
        __builtin_amdgcn_rcpf((1.0f + eo) * (ec + 1.0f));   // sig(o)*tanh(c)
}

#define PIN(f) asm volatile("" : "+v"(f.x), "+v"(f.y), "+v"(f.z), "+v"(f.w));
#define MFMA(af, b, c) __builtin_amdgcn_mfma_f32_16x16x32_f16(__builtin_bit_cast(half8, (af)), (b), (c), 0, 0, 0)

extern "C" __global__ __launch_bounds__(832, 4)
void lstm2_mfma_kernel(const float* __restrict__ x,
                       const float* __restrict__ W_ih0, const float* __restrict__ W_hh0,
                       const float* __restrict__ b_ih0, const float* __restrict__ b_hh0,
                       const float* __restrict__ W_ih1, const float* __restrict__ W_hh1,
                       const float* __restrict__ b_ih1, const float* __restrict__ b_hh1,
                       const float* __restrict__ fc_w, const float* __restrict__ fc_b,
                       float* __restrict__ out)
{
    // h-state in B-fragment layout: element (k, n) at (k>>5)*512 +
    // (((k&31)>>3)*16 + n)*8 + (k&7). k<50 = h, k==50 = x slot (H0 only).
    __shared__ _Float16 H0[2][1024];
    __shared__ _Float16 H1[2][1024];
    __shared__ float    hfin[HID * NB];   // fp32 h1^(TT) for the FC epilogue

    const int tid  = threadIdx.x;
    const int lane = tid & 63;
    const int wv   = tid >> 6;            // wave 0..12 = gate-row tile
    const int b0   = blockIdx.x * NB;

    for (int i = tid; i < 1024; i += 832) {
        H0[0][i] = (_Float16)0.f; H0[1][i] = (_Float16)0.f;
        H1[0][i] = (_Float16)0.f; H1[1][i] = (_Float16)0.f;
    }

    const int quad = lane >> 4;
    const int col  = lane & 15;           // batch column

    // ---- A-fragments (weights, exp2-prescaled), loaded once, pinned ----
    const int mrow  = lane & 15;          // A-row within tile
    const int gateA = mrow & 3;
    const int cellA = 4 * wv + (mrow >> 2);
    const float scA = (gateA == 2) ? 2.0f * LOG2E : -LOG2E;
    float4 A0c0 = make_wfrag(W_hh0, W_ih0, gateA, cellA, 0, quad, true,  scA);
    float4 A0c1 = make_wfrag(W_hh0, W_ih0, gateA, cellA, 1, quad, true,  scA);
    float4 Aic0 = make_wfrag(W_ih1, W_ih1, gateA, cellA, 0, quad, false, scA);
    float4 Aic1 = make_wfrag(W_ih1, W_ih1, gateA, cellA, 1, quad, false, scA);
    float4 Ahc0 = make_wfrag(W_hh1, W_hh1, gateA, cellA, 0, quad, false, scA);
    float4 Ahc1 = make_wfrag(W_hh1, W_hh1, gateA, cellA, 1, quad, false, scA);
    PIN(A0c0) PIN(A0c1) PIN(Aic0) PIN(Aic1) PIN(Ahc0) PIN(Ahc1)

    // ---- D-cell ownership: reg = gate, cell = 4*wv + quad, batch = col ----
    const int  cellD = 4 * wv + quad;
    const bool ewok  = (cellD < HID);
    f32x4 bias0, bias1;
    #pragma unroll
    for (int g = 0; g < 4; ++g) {
        const float s = (g == 2) ? 2.0f * LOG2E : -LOG2E;
        bias0[g] = ewok ? (b_ih0[g * HID + cellD] + b_hh0[g * HID + cellD]) * s : 0.f;
        bias1[g] = ewok ? (b_ih1[g * HID + cellD] + b_hh1[g * HID + cellD]) * s : 0.f;
    }
    // h write-back index in B-layout for (cellD, col)
    const int wi = (cellD >> 5) * 512 + (((cellD & 31) >> 3) * 16 + col) * 8 + (cellD & 7);

    // hoisted x row pointer for this thread's batch row (wave 0 lanes 0..15)
    const float* xp = x + (size_t)(b0 + (tid & 15)) * TT;
    const bool xth = (tid < NB);

    // x_0 into H0[0]'s x slot: k=50 -> chunk1, lane'=32+m, j=2
    if (xth) H0[0][512 + (32 + tid) * 8 + 2] = (_Float16)xp[0];

    float c0 = 0.f, c1 = 0.f;
    __syncthreads();

    #pragma unroll 2
    for (int u = 0; u <= TT; ++u) {
        const int pu = u & 1, pn = pu ^ 1;

        half8 b0c0 = *(half8*)(&H0[pu][lane * 8]);
        half8 b0c1 = *(half8*)(&H0[pu][512 + lane * 8]);

        float xr = 0.f;
        if (xth && (u + 1) < TT)
            xr = xp[u + 1];                            // issue early (L1-resident)

        if (u != TT) {   // ---- layer-0: gates0^u + in-register EW ----
            f32x4 acc = bias0;
            acc = MFMA(A0c0, b0c0, acc);
            acc = MFMA(A0c1, b0c1, acc);               // x slot k=50 included
            const float h = cell_update(acc, c0);
            if (ewok) H0[pn][wi] = (_Float16)h;        // h0^{u+1}
        }
        if (u != 0) {    // ---- layer-1: gates1^{u-1} + in-register EW ----
            half8 b1c0 = *(half8*)(&H1[pn][lane * 8]);
            half8 b1c1 = *(half8*)(&H1[pn][512 + lane * 8]);
            f32x4 acc = bias1;
            acc = MFMA(Aic0, b0c0, acc);               // Wi1 . h0^u
            acc = MFMA(Aic1, b0c1, acc);               // (x slot hits zero rows)
            acc = MFMA(Ahc0, b1c0, acc);               // Wh1 . h1^{u-1}
            acc = MFMA(Ahc1, b1c1, acc);
            const float h = cell_update(acc, c1);
            if (ewok) {
                H1[pu][wi] = (_Float16)h;              // h1^u
                if (u == TT) hfin[cellD * NB + col] = h;
            }
        }
        if (xth && (u + 1) < TT)
            H0[pn][512 + (32 + tid) * 8 + 2] = (_Float16)xr;   // x_{u+1} slot
        __syncthreads();
    }

    // ---------- FC epilogue: out[b] = fc_b + fc_w . h1^(TT)[b,:] ----------
    if (tid < NB) {
        float s = fc_b[0];
        for (int k = 0; k < HID; ++k)
            s += fc_w[k] * hfin[k * NB + tid];
        out[b0 + tid] = s;
    }
}

extern "C" void kernel_launch(void* const* d_in, const int* in_sizes, int n_in,
                              void* d_out, int out_size, void* d_ws, size_t ws_size,
                              hipStream_t stream) {
    (void)in_sizes; (void)n_in; (void)d_ws; (void)ws_size; (void)out_size;
    const float* x     = (const float*)d_in[0];
    const float* W_ih0 = (const float*)d_in[1];
    const float* W_hh0 = (const float*)d_in[2];
    const float* b_ih0 = (const float*)d_in[3];
    const float* b_hh0 = (const float*)d_in[4];
    const float* W_ih1 = (const float*)d_in[5];
    const float* W_hh1 = (const float*)d_in[6];
    const float* b_ih1 = (const float*)d_in[7];
    const float* b_hh1 = (const float*)d_in[8];
    const float* fc_w  = (const float*)d_in[9];
    const float* fc_b  = (const float*)d_in[10];

    dim3 grid(4096 / NB);   // 256 blocks, 1 per CU
    dim3 block(832);        // 13 waves
    lstm2_mfma_kernel<<<grid, block, 0, stream>>>(
        x, W_ih0, W_hh0, b_ih0, b_hh0,
        W_ih1, W_hh1, b_ih1, b_hh1,
        fc_w, fc_b, (float*)d_out);
}